// Round 13
// baseline (865.813 us; speedup 1.0000x reference)
//
#include <hip/hip_runtime.h>
#include <hip/hip_bf16.h>

// FacePartGAT: dense-graph GATConv x2 + mean + fc on MI355X. ALL I/O fp32.
// e[i,j] = leaky_relu(t_i + s_j) => softmax aggregation factorizes after
// sorting sources by s_j. Round 13: TABLE-FREE merge-join. Dests are sorted
// by thr=-t as well; one fused kernel per layer builds per-chunk prefix
// vectors in LDS and serves the dests whose split point lands in its chunk
// (suffix = Total - prefix). Eliminates the 45 MB SS/PP table round-trip
// (passC write + attend read) and the full-4096 per-dest binary search.
// 12 dispatches. grid.sync (r8) and narrow grids (r9) remain forbidden.

#define NNODE 4096
#define CDIM 128
#define TW 132           // passA partial width: 128 features + z at col 128
#define NEG 0.2f
#define CHUNK 64
#define NCHUNK 64        // NNODE / CHUNK
#define SEG 8
#define SEGK (NNODE / SEG)  // 512

typedef __bf16 bf16x8 __attribute__((ext_vector_type(8)));
typedef float f32x4 __attribute__((ext_vector_type(4)));

__device__ __forceinline__ unsigned short f2b(float f) {
  unsigned int u = __float_as_uint(f);
  u += 0x7fffu + ((u >> 16) & 1u);  // RTNE
  return (unsigned short)(u >> 16);
}

// One kernel: convert x -> bf16; transpose W1, W2; zero s/t/colsum region.
__global__ __launch_bounds__(256) void prep_kernel(const float* __restrict__ x,
                                                   const float* __restrict__ W1,
                                                   const float* __restrict__ W2,
                                                   unsigned short* __restrict__ xb,
                                                   unsigned short* __restrict__ W1t,
                                                   unsigned short* __restrict__ W2t,
                                                   float* __restrict__ zbase) {
  __shared__ float tile[64][65];
  int b = blockIdx.x, t = threadIdx.x;
  if (b < 3072) {  // convert x: 4096*768/4 quads
    int i = b * 256 + t;
    float4 v = ((const float4*)x)[i];
    ushort4 o;
    o.x = f2b(v.x); o.y = f2b(v.y); o.z = f2b(v.z); o.w = f2b(v.w);
    ((ushort4*)xb)[i] = o;
    return;
  }
  if (b >= 3072 + 96 + 16) {  // zero s1,t1,s2,t2,colsum: 41088 floats = 10272 quads
    int idx = (b - 3072 - 96 - 16) * 256 + t;
    if (idx < 10272) {
      float4 z = {0.f, 0.f, 0.f, 0.f};
      ((float4*)zbase)[idx] = z;
    }
    return;
  }
  const float* W; unsigned short* Wt; int K, N, n0, k0;
  if (b < 3072 + 96) {  // W1 [768,512] -> W1t [512,768]
    int b2 = b - 3072; W = W1; Wt = W1t; K = 768; N = 512;
    n0 = (b2 & 7) * 64; k0 = (b2 >> 3) * 64;
  } else {              // W2 [512,128] -> W2t [128,512]
    int b3 = b - 3072 - 96; W = W2; Wt = W2t; K = 512; N = 128;
    n0 = (b3 & 1) * 64; k0 = (b3 >> 1) * 64;
  }
  for (int p = 0; p < 16; p++) {
    int e = p * 256 + t;
    int rr = e >> 6, cc = e & 63;
    tile[rr][cc] = W[(size_t)(k0 + rr) * N + n0 + cc];
  }
  __syncthreads();
  for (int p = 0; p < 16; p++) {
    int e = p * 256 + t;
    int rr = e >> 6, cc = e & 63;
    Wt[(size_t)(n0 + rr) * K + k0 + cc] = f2b(tile[cc][rr]);
  }
}

// C[M,N] = A[M,K] x Bt[N,K]^T, both bf16 K-contig. Register prefetch.
// Fused epilogue: s[h][n] += h.asrc ; t[h][n] += -(h.adst)  (t holds thr=-t).
template <int BM, int BN>
__global__ __launch_bounds__(256) void mfma_gemm_bt(const unsigned short* __restrict__ A,
                                                    const unsigned short* __restrict__ Bt,
                                                    float* __restrict__ C,
                                                    const float* __restrict__ asrc,
                                                    const float* __restrict__ adst,
                                                    float* __restrict__ s,
                                                    float* __restrict__ t,
                                                    int M, int N, int K) {
  __shared__ __align__(16) unsigned short As[BM * 40];
  __shared__ __align__(16) unsigned short Bs[BN * 40];
  constexpr int WM = BM / 2, WN = BN / 2;
  constexpr int FI = WM / 16, FJ = WN / 16;
  constexpr int EA = BM * 32 / 8;
  constexpr int EB = BN * 32 / 8;
  constexpr int NA = (EA + 255) / 256;
  constexpr int NB = (EB + 255) / 256;
  int tid = threadIdx.x;
  int lane = tid & 63, wave = tid >> 6;
  int wm = (wave >> 1) * WM, wn = (wave & 1) * WN;
  int m0 = blockIdx.y * BM, n0 = blockIdx.x * BN;
  int fm = lane & 15, fq = lane >> 4;
  f32x4 acc[FI][FJ] = {};
  uint4 ar[NA], br[NB];
#pragma unroll
  for (int q = 0; q < NA; q++) {
    int e = q * 256 + tid;
    if (e < EA) {
      int r = e >> 2, kk = (e & 3) * 8;
      ar[q] = *(const uint4*)(A + (size_t)(m0 + r) * K + kk);
    }
  }
#pragma unroll
  for (int q = 0; q < NB; q++) {
    int e = q * 256 + tid;
    if (e < EB) {
      int r = e >> 2, kk = (e & 3) * 8;
      br[q] = *(const uint4*)(Bt + (size_t)(n0 + r) * K + kk);
    }
  }
  for (int k0 = 0; k0 < K; k0 += 32) {
    __syncthreads();
#pragma unroll
    for (int q = 0; q < NA; q++) {
      int e = q * 256 + tid;
      if (e < EA) {
        int r = e >> 2, kk = (e & 3) * 8;
        *(uint4*)&As[r * 40 + kk] = ar[q];
      }
    }
#pragma unroll
    for (int q = 0; q < NB; q++) {
      int e = q * 256 + tid;
      if (e < EB) {
        int r = e >> 2, kk = (e & 3) * 8;
        *(uint4*)&Bs[r * 40 + kk] = br[q];
      }
    }
    __syncthreads();
    if (k0 + 32 < K) {
#pragma unroll
      for (int q = 0; q < NA; q++) {
        int e = q * 256 + tid;
        if (e < EA) {
          int r = e >> 2, kk = (e & 3) * 8;
          ar[q] = *(const uint4*)(A + (size_t)(m0 + r) * K + k0 + 32 + kk);
        }
      }
#pragma unroll
      for (int q = 0; q < NB; q++) {
        int e = q * 256 + tid;
        if (e < EB) {
          int r = e >> 2, kk = (e & 3) * 8;
          br[q] = *(const uint4*)(Bt + (size_t)(n0 + r) * K + k0 + 32 + kk);
        }
      }
    }
    bf16x8 af[FI], bfr[FJ];
#pragma unroll
    for (int i = 0; i < FI; i++)
      af[i] = *(const bf16x8*)&As[(wm + i * 16 + fm) * 40 + fq * 8];
#pragma unroll
    for (int j = 0; j < FJ; j++)
      bfr[j] = *(const bf16x8*)&Bs[(wn + j * 16 + fm) * 40 + fq * 8];
#pragma unroll
    for (int i = 0; i < FI; i++)
#pragma unroll
      for (int j = 0; j < FJ; j++)
        acc[i][j] = __builtin_amdgcn_mfma_f32_16x16x32_bf16(af[i], bfr[j], acc[i][j], 0, 0, 0);
  }
#pragma unroll
  for (int i = 0; i < FI; i++) {
#pragma unroll
    for (int j = 0; j < FJ; j++) {
      int r = m0 + wm + i * 16 + fq * 4;
      int ccol = n0 + wn + j * 16 + fm;
#pragma unroll
      for (int reg = 0; reg < 4; reg++)
        C[(size_t)(r + reg) * N + ccol] = acc[i][j][reg];
    }
  }
  // Fused st epilogue (t negated: t-array holds thr = -t).
  int hh = (n0 + wn) / CDIM;
  float av[FJ], dv[FJ];
#pragma unroll
  for (int j = 0; j < FJ; j++) {
    int col = (n0 + wn + j * 16 + fm) & (CDIM - 1);
    av[j] = asrc[hh * CDIM + col];
    dv[j] = adst[hh * CDIM + col];
  }
#pragma unroll
  for (int i = 0; i < FI; i++) {
#pragma unroll
    for (int reg = 0; reg < 4; reg++) {
      float ssum = 0.f, tsum = 0.f;
#pragma unroll
      for (int j = 0; j < FJ; j++) {
        ssum = fmaf(acc[i][j][reg], av[j], ssum);
        tsum = fmaf(acc[i][j][reg], dv[j], tsum);
      }
#pragma unroll
      for (int o = 1; o < 16; o <<= 1) {
        ssum += __shfl_xor(ssum, o, 64);
        tsum += __shfl_xor(tsum, o, 64);
      }
      if (fm == 0) {
        int r = m0 + wm + i * 16 + fq * 4 + reg;
        atomicAdd(&s[(size_t)hh * NNODE + r], ssum);
        atomicAdd(&t[(size_t)hh * NNODE + r], -tsum);
      }
    }
  }
}

// Segmented rank sort over NK contiguous key arrays (s rows then thr rows).
__global__ __launch_bounds__(256) void rank_count_kernel(const float* __restrict__ keysg,
                                                         int* __restrict__ partial) {
  __shared__ __align__(16) float keys[SEGK];
  int z = blockIdx.z, seg = blockIdx.y, tid = threadIdx.x;
  const float* sp = keysg + (size_t)z * NNODE;
  for (int k = tid; k < SEGK; k += 256) keys[k] = sp[seg * SEGK + k];
  __syncthreads();
  int mi = blockIdx.x * 256 + tid;
  float mk = sp[mi];
  int jbase = seg * SEGK;
  int cnt = 0;
#pragma unroll 4
  for (int j = 0; j < SEGK; j += 4) {
    float4 kv = *(const float4*)&keys[j];
    cnt += (kv.x < mk) || (kv.x == mk && (jbase + j + 0) < mi);
    cnt += (kv.y < mk) || (kv.y == mk && (jbase + j + 1) < mi);
    cnt += (kv.z < mk) || (kv.z == mk && (jbase + j + 2) < mi);
    cnt += (kv.w < mk) || (kv.w == mk && (jbase + j + 3) < mi);
  }
  partial[((size_t)z * SEG + seg) * NNODE + mi] = cnt;
}

__global__ __launch_bounds__(256) void rank_scatter_kernel(const float* __restrict__ keysg,
                                                           const int* __restrict__ partial,
                                                           float* __restrict__ ss,
                                                           int* __restrict__ si) {
  int z = blockIdx.y;
  int mi = blockIdx.x * 256 + threadIdx.x;
  int rank = 0;
#pragma unroll
  for (int g = 0; g < SEG; g++) rank += partial[((size_t)z * SEG + g) * NNODE + mi];
  ss[(size_t)z * NNODE + rank] = keysg[(size_t)z * NNODE + mi];
  si[(size_t)z * NNODE + rank] = mi;
}

// Pass A: per-chunk partial sums of e^{s}*h (P) and e^{0.2s}*h (M); z at 128.
__global__ __launch_bounds__(128) void passA_kernel(const float* __restrict__ h,
                                                    const float* __restrict__ ss,
                                                    const int* __restrict__ si,
                                                    float* __restrict__ partP,
                                                    float* __restrict__ partM, int H) {
  __shared__ float eP[CHUNK], eM[CHUNK];
  __shared__ int ids[CHUNK];
  int b = blockIdx.x, hh = b / NCHUNK, ci = b % NCHUNK;
  int c = threadIdx.x;
  int HC = H * CDIM;
  int base = ci * CHUNK;
  if (c < CHUNK) {
    float sv = ss[(size_t)hh * NNODE + base + c];
    ids[c] = si[(size_t)hh * NNODE + base + c];
    eP[c] = expf(sv);
    eM[c] = expf(NEG * sv);
  }
  __syncthreads();
  float sp = 0.f, sm = 0.f;
  for (int kb = 0; kb < CHUNK; kb += 8) {
    float v[8];
#pragma unroll
    for (int j = 0; j < 8; j++)
      v[j] = h[(size_t)ids[kb + j] * HC + hh * CDIM + c];
#pragma unroll
    for (int j = 0; j < 8; j++) {
      sp = fmaf(eP[kb + j], v[j], sp);
      sm = fmaf(eM[kb + j], v[j], sm);
    }
  }
  size_t o = ((size_t)hh * NCHUNK + ci) * TW;
  partP[o + c] = sp;
  partM[o + c] = sm;
  if (c == 0) {
    float zp = 0.f, zm = 0.f;
#pragma unroll
    for (int k = 0; k < CHUNK; k++) { zp += eP[k]; zm += eM[k]; }
    partP[o + 128] = zp;
    partM[o + 128] = zm;
  }
}

// Fused tables+attend (merge-join). Block (hh, ci, sub): builds per-position
// prefix vectors (both branches) for source chunk ci in LDS, then serves the
// thr-sorted dests whose split point lands in this chunk.
// num = wp*(TotP - prefP[L]) + wm*prefM[L];  Z analog with z scalars.
template <typename OUT, int H, int SUBS, bool COLSUM>
__global__ __launch_bounds__(128) void fused_attend_kernel(
    const float* __restrict__ h,
    const float* __restrict__ sS, const int* __restrict__ sI,
    const float* __restrict__ sT, const int* __restrict__ iT,
    const float* __restrict__ partP, const float* __restrict__ partM,
    const float* __restrict__ bias, OUT* __restrict__ out,
    float* __restrict__ colsum) {
  __shared__ float PMp[CHUNK + 1][CDIM];   // prefix of e^{0.2s} h  (33.3 KB)
  __shared__ float PPp[CHUNK + 1][CDIM];   // prefix of e^{s} h     (33.3 KB)
  __shared__ float keys[CHUNK], ePl[CHUNK], eMl[CHUNK];
  __shared__ int ids[CHUNK];
  __shared__ float zMp[CHUNK + 1], zPp[CHUNK + 1];
  __shared__ float totzp_sh;
  int bx = blockIdx.x;
  int ci = bx / SUBS, sub = bx % SUBS;
  int hh = blockIdx.y;
  int c = threadIdx.x;
  int HC = H * CDIM;
  int base = ci * CHUNK;
  if (c < CHUNK) {
    float sv = sS[(size_t)hh * NNODE + base + c];
    ids[c] = sI[(size_t)hh * NNODE + base + c];
    keys[c] = sv;
    ePl[c] = expf(sv);
    eMl[c] = expf(NEG * sv);
  }
  __syncthreads();
  // carry combine from passA partials (batched 16)
  float cmM = 0.f, cmP = 0.f, totP = 0.f;
  for (int g0 = 0; g0 < NCHUNK; g0 += 16) {
    float vm[16], vp[16];
#pragma unroll
    for (int j = 0; j < 16; j++) {
      size_t o = ((size_t)hh * NCHUNK + g0 + j) * TW + c;
      vm[j] = partM[o];
      vp[j] = partP[o];
    }
#pragma unroll
    for (int j = 0; j < 16; j++) {
      totP += vp[j];
      if (g0 + j < ci) { cmM += vm[j]; cmP += vp[j]; }
    }
  }
  float zcM = 0.f, zcP = 0.f, totZP = 0.f;
  if (c == 0) {
    for (int g0 = 0; g0 < NCHUNK; g0 += 16) {
      float vm[16], vp[16];
#pragma unroll
      for (int j = 0; j < 16; j++) {
        size_t o = ((size_t)hh * NCHUNK + g0 + j) * TW + 128;
        vm[j] = partM[o];
        vp[j] = partP[o];
      }
#pragma unroll
      for (int j = 0; j < 16; j++) {
        totZP += vp[j];
        if (g0 + j < ci) { zcM += vm[j]; zcP += vp[j]; }
      }
    }
  }
  // build per-position prefixes (h gathered in 8-batches)
  float runm = cmM, runp = cmP;
  for (int kb = 0; kb < CHUNK; kb += 8) {
    float v[8];
#pragma unroll
    for (int j = 0; j < 8; j++)
      v[j] = h[(size_t)ids[kb + j] * HC + hh * CDIM + c];
#pragma unroll
    for (int j = 0; j < 8; j++) {
      int k = kb + j;
      PMp[k][c] = runm;
      PPp[k][c] = runp;
      runm = fmaf(eMl[k], v[j], runm);
      runp = fmaf(ePl[k], v[j], runp);
    }
  }
  PMp[CHUNK][c] = runm;
  PPp[CHUNK][c] = runp;
  if (c == 0) {
    float zrm = zcM, zrp = zcP;
    for (int k = 0; k < CHUNK; k++) {
      zMp[k] = zrm; zPp[k] = zrp;
      zrm += eMl[k]; zrp += ePl[k];
    }
    zMp[CHUNK] = zrm; zPp[CHUNK] = zrp;
    totzp_sh = totZP;
  }
  __syncthreads();
  float totZPl = totzp_sh;
  // dest range: thr-sorted dests with split point in (sS[base-1], sS[base+63]]
  const float* sTp = sT + (size_t)hh * NNODE;
  const int* iTp = iT + (size_t)hh * NNODE;
  float loKey = (ci > 0) ? sS[(size_t)hh * NNODE + base - 1] : -3.4e38f;
  int lo = 0, hi = NNODE;
  while (lo < hi) { int mid = (lo + hi) >> 1; if (sTp[mid] <= loKey) lo = mid + 1; else hi = mid; }
  int pLo = lo;
  int pHi;
  if (ci == NCHUNK - 1) pHi = NNODE;
  else {
    float hiKey = keys[CHUNK - 1];
    lo = pLo; hi = NNODE;
    while (lo < hi) { int mid = (lo + hi) >> 1; if (sTp[mid] <= hiKey) lo = mid + 1; else hi = mid; }
    pHi = lo;
  }
  int R = pHi - pLo;
  int per = (R + SUBS - 1) / SUBS;
  int myLo = pLo + sub * per;
  int myHi = myLo + per < pHi ? myLo + per : pHi;
  float bval = bias[hh * CDIM + c];
  float csum = 0.f;
  for (int p = myLo; p < myHi; p++) {
    float thr = sTp[p];
    int n = iTp[p];
    // local lower_bound over the 64 chunk keys: first k with keys[k] >= thr
    int l = 0, hh2 = CHUNK;
    while (l < hh2) { int mid = (l + hh2) >> 1; if (keys[mid] < thr) l = mid + 1; else hh2 = mid; }
    float wp = expf(-thr), wm = expf(-NEG * thr);
    float num = wp * (totP - PPp[l][c]) + wm * PMp[l][c];
    float Z = wp * (totZPl - zPp[l]) + wm * zMp[l];
    float o = num / Z + bval;
    float r = (o > 0.f) ? o : (expf(o) - 1.f);
    if constexpr (sizeof(OUT) == 2)
      out[(size_t)n * HC + hh * CDIM + c] = f2b(r);
    else
      out[(size_t)n * HC + hh * CDIM + c] = r;
    if constexpr (COLSUM) csum += r;
  }
  if constexpr (COLSUM) {
    if (myHi > myLo) atomicAdd(&colsum[c], csum);
  }
}

__global__ __launch_bounds__(256) void fc_kernel(const float* __restrict__ colsum,
                                                 const float* __restrict__ fcW,
                                                 const float* __restrict__ fcb,
                                                 float* __restrict__ out) {
  int d = blockIdx.x * 256 + threadIdx.x;  // 768 total
  float acc = fcb[d];
  const float invN = 1.f / NNODE;
  for (int c2 = 0; c2 < CDIM; c2++) acc = fmaf(colsum[c2] * invN, fcW[c2 * 768 + d], acc);
  out[d] = acc;
}

extern "C" void kernel_launch(void* const* d_in, const int* in_sizes, int n_in,
                              void* d_out, int out_size, void* d_ws, size_t ws_size,
                              hipStream_t stream) {
  const float* x   = (const float*)d_in[0];
  const float* W1  = (const float*)d_in[1];
  const float* as1 = (const float*)d_in[2];
  const float* ad1 = (const float*)d_in[3];
  const float* b1  = (const float*)d_in[4];
  const float* W2  = (const float*)d_in[5];
  const float* as2 = (const float*)d_in[6];
  const float* ad2 = (const float*)d_in[7];
  const float* b2  = (const float*)d_in[8];
  const float* fcW = (const float*)d_in[9];
  const float* fcb = (const float*)d_in[10];

  float* ws = (float*)d_ws;
  size_t off = 0;
  auto alloc = [&](size_t nfloats) { float* p = ws + off; off += nfloats; return p; };

  float* h1  = alloc((size_t)NNODE * 512);
  float* x2f = alloc((size_t)NNODE * 256 + 64 + 16384);  // x2b bf16 + W2t bf16
  float* h2  = alloc((size_t)NNODE * 128);
  float* x3  = alloc((size_t)NNODE * 128);
  // zero region: s1(4N), t1(4N), s2(N), t2(N), colsum(128) = 41088 floats
  float* s1  = alloc((size_t)4 * NNODE);
  float* t1  = alloc((size_t)4 * NNODE);   // holds thr = -t
  float* s2  = alloc(NNODE);
  float* t2  = alloc(NNODE);
  float* mv  = alloc(128);
  float* sA1 = alloc((size_t)8 * NNODE);   // sorted: rows 0-3 s, rows 4-7 thr
  int*   iA1 = (int*)alloc((size_t)8 * NNODE);
  float* pP1 = alloc((size_t)4 * NCHUNK * TW);
  float* pM1 = alloc((size_t)4 * NCHUNK * TW);
  float* sA2 = alloc((size_t)2 * NNODE);   // row 0 s, row 1 thr
  int*   iA2 = (int*)alloc((size_t)2 * NNODE);
  float* pP2 = alloc((size_t)NCHUNK * TW);
  float* pM2 = alloc((size_t)NCHUNK * TW);
  int*   rparts = (int*)alloc((size_t)8 * SEG * NNODE);
  float* xbf = alloc((size_t)NNODE * 384);      // xb bf16 4096x768
  float* w1f = alloc((size_t)512 * 384);        // W1t bf16 512x768

  unsigned short* xb  = (unsigned short*)xbf;
  unsigned short* W1t = (unsigned short*)w1f;
  unsigned short* x2b = (unsigned short*)x2f;
  unsigned short* W2t = (unsigned short*)(x2f + NNODE * 256 + 64);

  // Prep: convert x + transpose/cast W1, W2 + zero s/t/colsum
  prep_kernel<<<3072 + 96 + 16 + 41, 256, 0, stream>>>(x, W1, W2, xb, W1t, W2t, s1);
  // Layer 1 (st fused into GEMM epilogue; s1/t1 contiguous -> 8 key rows)
  mfma_gemm_bt<64, 64><<<dim3(512 / 64, NNODE / 64), 256, 0, stream>>>(
      xb, W1t, h1, as1, ad1, s1, t1, NNODE, 512, 768);
  rank_count_kernel<<<dim3(NNODE / 256, SEG, 8), 256, 0, stream>>>(s1, rparts);
  rank_scatter_kernel<<<dim3(NNODE / 256, 8), 256, 0, stream>>>(s1, rparts, sA1, iA1);
  passA_kernel<<<4 * NCHUNK, 128, 0, stream>>>(h1, sA1, iA1, pP1, pM1, 4);
  fused_attend_kernel<unsigned short, 4, 1, false><<<dim3(NCHUNK, 4), 128, 0, stream>>>(
      h1, sA1, iA1, sA1 + (size_t)4 * NNODE, iA1 + (size_t)4 * NNODE,
      pP1, pM1, b1, x2b, nullptr);
  // Layer 2
  mfma_gemm_bt<32, 64><<<dim3(128 / 64, NNODE / 32), 256, 0, stream>>>(
      x2b, W2t, h2, as2, ad2, s2, t2, NNODE, 128, 512);
  rank_count_kernel<<<dim3(NNODE / 256, SEG, 2), 256, 0, stream>>>(s2, rparts);
  rank_scatter_kernel<<<dim3(NNODE / 256, 2), 256, 0, stream>>>(s2, rparts, sA2, iA2);
  passA_kernel<<<NCHUNK, 128, 0, stream>>>(h2, sA2, iA2, pP2, pM2, 1);
  fused_attend_kernel<float, 1, 4, true><<<dim3(NCHUNK * 4, 1), 128, 0, stream>>>(
      h2, sA2, iA2, sA2 + (size_t)NNODE, iA2 + (size_t)NNODE,
      pP2, pM2, b2, x3, mv);
  // Readout
  fc_kernel<<<3, 256, 0, stream>>>(mv, fcW, fcb, (float*)d_out);
}

// Round 14
// 228.547 us; speedup vs baseline: 3.7883x; 3.7883x over previous
//
#include <hip/hip_runtime.h>
#include <hip/hip_bf16.h>

// FacePartGAT: dense-graph GATConv x2 + mean + fc on MI355X. ALL I/O fp32.
// e[i,j] = leaky_relu(t_i + s_j) => softmax aggregation factorizes after
// sorting sources by s_j (prefix/suffix tables + binary search). Exact.
// Round 14: REVERT to round-11 (best measured: 224.85 us).
// Closed routes (measured): cooperative grid.sync = ~60us each (r8, 8-XCD
// coherence); occupancy-collapsing fusions = 10x (r9 sort, r13 merge-join
// straggler at 0.2% occupancy); boundary-removal fusions pay back their
// savings in epilogue overhead (r12: 14 dispatches, +8us). Residual above
// ~100us phase work = ~17-stage serial chain x ~7us/boundary + 42us harness
// workspace re-poison — a launch-latency floor, not a HW roofline.

#define NNODE 4096
#define CDIM 128
#define TW 132           // table width: 128 features + z at col 128
#define NEG 0.2f
#define CHUNK 64
#define NCHUNK 64        // NNODE / CHUNK
#define SEG 8
#define SEGK (NNODE / SEG)  // 512

typedef __bf16 bf16x8 __attribute__((ext_vector_type(8)));
typedef float f32x4 __attribute__((ext_vector_type(4)));

__device__ __forceinline__ unsigned short f2b(float f) {
  unsigned int u = __float_as_uint(f);
  u += 0x7fffu + ((u >> 16) & 1u);  // RTNE
  return (unsigned short)(u >> 16);
}

// One kernel: [0,3072) convert x -> bf16; [3072,3168) transpose W1; rest W2.
__global__ __launch_bounds__(256) void prep_kernel(const float* __restrict__ x,
                                                   const float* __restrict__ W1,
                                                   const float* __restrict__ W2,
                                                   unsigned short* __restrict__ xb,
                                                   unsigned short* __restrict__ W1t,
                                                   unsigned short* __restrict__ W2t) {
  __shared__ float tile[64][65];
  int b = blockIdx.x, t = threadIdx.x;
  if (b < 3072) {  // convert x: 4096*768/4 quads
    int i = b * 256 + t;
    float4 v = ((const float4*)x)[i];
    ushort4 o;
    o.x = f2b(v.x); o.y = f2b(v.y); o.z = f2b(v.z); o.w = f2b(v.w);
    ((ushort4*)xb)[i] = o;
    return;
  }
  const float* W; unsigned short* Wt; int K, N, n0, k0;
  if (b < 3072 + 96) {  // W1 [768,512] -> W1t [512,768]
    int b2 = b - 3072; W = W1; Wt = W1t; K = 768; N = 512;
    n0 = (b2 & 7) * 64; k0 = (b2 >> 3) * 64;
  } else {              // W2 [512,128] -> W2t [128,512]
    int b3 = b - 3072 - 96; W = W2; Wt = W2t; K = 512; N = 128;
    n0 = (b3 & 1) * 64; k0 = (b3 >> 1) * 64;
  }
  for (int p = 0; p < 16; p++) {
    int e = p * 256 + t;
    int rr = e >> 6, cc = e & 63;
    tile[rr][cc] = W[(size_t)(k0 + rr) * N + n0 + cc];
  }
  __syncthreads();
  for (int p = 0; p < 16; p++) {
    int e = p * 256 + t;
    int rr = e >> 6, cc = e & 63;  // rr: n-dir, cc: k-dir
    Wt[(size_t)(n0 + rr) * K + k0 + cc] = f2b(tile[cc][rr]);
  }
}

// C[M,N] = A[M,K] x Bt[N,K]^T, both bf16 K-contig. BK=32, 256 thr = 4 waves
// (2x2). Register prefetch: tile k+1 global loads issued between the LDS
// barrier and the MFMA section so global latency overlaps compute.
template <int BM, int BN>
__global__ __launch_bounds__(256) void mfma_gemm_bt(const unsigned short* __restrict__ A,
                                                    const unsigned short* __restrict__ Bt,
                                                    float* __restrict__ C,
                                                    int M, int N, int K) {
  __shared__ __align__(16) unsigned short As[BM * 40];
  __shared__ __align__(16) unsigned short Bs[BN * 40];
  constexpr int WM = BM / 2, WN = BN / 2;
  constexpr int FI = WM / 16, FJ = WN / 16;
  constexpr int EA = BM * 32 / 8;
  constexpr int EB = BN * 32 / 8;
  constexpr int NA = (EA + 255) / 256;
  constexpr int NB = (EB + 255) / 256;
  int tid = threadIdx.x;
  int lane = tid & 63, wave = tid >> 6;
  int wm = (wave >> 1) * WM, wn = (wave & 1) * WN;
  int m0 = blockIdx.y * BM, n0 = blockIdx.x * BN;
  int fm = lane & 15, fq = lane >> 4;
  f32x4 acc[FI][FJ] = {};
  uint4 ar[NA], br[NB];
  // preload tile 0
#pragma unroll
  for (int q = 0; q < NA; q++) {
    int e = q * 256 + tid;
    if (e < EA) {
      int r = e >> 2, kk = (e & 3) * 8;
      ar[q] = *(const uint4*)(A + (size_t)(m0 + r) * K + kk);
    }
  }
#pragma unroll
  for (int q = 0; q < NB; q++) {
    int e = q * 256 + tid;
    if (e < EB) {
      int r = e >> 2, kk = (e & 3) * 8;
      br[q] = *(const uint4*)(Bt + (size_t)(n0 + r) * K + kk);
    }
  }
  for (int k0 = 0; k0 < K; k0 += 32) {
    __syncthreads();  // previous iter's ds_reads done before overwrite
#pragma unroll
    for (int q = 0; q < NA; q++) {
      int e = q * 256 + tid;
      if (e < EA) {
        int r = e >> 2, kk = (e & 3) * 8;
        *(uint4*)&As[r * 40 + kk] = ar[q];
      }
    }
#pragma unroll
    for (int q = 0; q < NB; q++) {
      int e = q * 256 + tid;
      if (e < EB) {
        int r = e >> 2, kk = (e & 3) * 8;
        *(uint4*)&Bs[r * 40 + kk] = br[q];
      }
    }
    __syncthreads();
    // prefetch tile k+1 (in flight during ds_read + MFMA below)
    if (k0 + 32 < K) {
#pragma unroll
      for (int q = 0; q < NA; q++) {
        int e = q * 256 + tid;
        if (e < EA) {
          int r = e >> 2, kk = (e & 3) * 8;
          ar[q] = *(const uint4*)(A + (size_t)(m0 + r) * K + k0 + 32 + kk);
        }
      }
#pragma unroll
      for (int q = 0; q < NB; q++) {
        int e = q * 256 + tid;
        if (e < EB) {
          int r = e >> 2, kk = (e & 3) * 8;
          br[q] = *(const uint4*)(Bt + (size_t)(n0 + r) * K + k0 + 32 + kk);
        }
      }
    }
    bf16x8 af[FI], bfr[FJ];
#pragma unroll
    for (int i = 0; i < FI; i++)
      af[i] = *(const bf16x8*)&As[(wm + i * 16 + fm) * 40 + fq * 8];
#pragma unroll
    for (int j = 0; j < FJ; j++)
      bfr[j] = *(const bf16x8*)&Bs[(wn + j * 16 + fm) * 40 + fq * 8];
#pragma unroll
    for (int i = 0; i < FI; i++)
#pragma unroll
      for (int j = 0; j < FJ; j++)
        acc[i][j] = __builtin_amdgcn_mfma_f32_16x16x32_bf16(af[i], bfr[j], acc[i][j], 0, 0, 0);
  }
#pragma unroll
  for (int i = 0; i < FI; i++) {
#pragma unroll
    for (int j = 0; j < FJ; j++) {
      int r = m0 + wm + i * 16 + fq * 4;
      int ccol = n0 + wn + j * 16 + fm;
#pragma unroll
      for (int reg = 0; reg < 4; reg++)
        C[(size_t)(r + reg) * N + ccol] = acc[i][j][reg];
    }
  }
}

// s[h][n], t[h][n] via one wave per (node, head); shuffle reduce, no LDS.
__global__ void st_kernel(const float* __restrict__ h,
                          const float* __restrict__ asrc,
                          const float* __restrict__ adst,
                          float* __restrict__ s, float* __restrict__ t, int H) {
  int n = blockIdx.x;
  int wave = threadIdx.x >> 6, lane = threadIdx.x & 63;
  int HC = H * CDIM;
  float2 hv = *(const float2*)&h[(size_t)n * HC + wave * CDIM + lane * 2];
  float2 av = *(const float2*)&asrc[wave * CDIM + lane * 2];
  float2 dv = *(const float2*)&adst[wave * CDIM + lane * 2];
  float ps = hv.x * av.x + hv.y * av.y;
  float pt = hv.x * dv.x + hv.y * dv.y;
#pragma unroll
  for (int o = 32; o > 0; o >>= 1) {
    ps += __shfl_down(ps, o, 64);
    pt += __shfl_down(pt, o, 64);
  }
  if (lane == 0) {
    s[(size_t)wave * NNODE + n] = ps;
    t[(size_t)wave * NNODE + n] = pt;
  }
}

// Segmented rank sort, pass 1: partial rank counts over a 512-key segment.
__global__ __launch_bounds__(256) void rank_count_kernel(const float* __restrict__ s,
                                                         int* __restrict__ partial) {
  __shared__ __align__(16) float keys[SEGK];
  int hh = blockIdx.z, seg = blockIdx.y, tid = threadIdx.x;
  const float* sp = s + (size_t)hh * NNODE;
  for (int k = tid; k < SEGK; k += 256) keys[k] = sp[seg * SEGK + k];
  __syncthreads();
  int mi = blockIdx.x * 256 + tid;
  float mk = sp[mi];
  int jbase = seg * SEGK;
  int cnt = 0;
#pragma unroll 4
  for (int j = 0; j < SEGK; j += 4) {
    float4 kv = *(const float4*)&keys[j];
    int jj = jbase + j;
    cnt += (kv.x < mk) || (kv.x == mk && (jj + 0) < mi);
    cnt += (kv.y < mk) || (kv.y == mk && (jj + 1) < mi);
    cnt += (kv.z < mk) || (kv.z == mk && (jj + 2) < mi);
    cnt += (kv.w < mk) || (kv.w == mk && (jj + 3) < mi);
  }
  partial[((size_t)hh * SEG + seg) * NNODE + mi] = cnt;
}

// Pass 2: combine partials, scatter keys+indices to sorted position.
__global__ __launch_bounds__(256) void rank_scatter_kernel(const float* __restrict__ s,
                                                           const int* __restrict__ partial,
                                                           float* __restrict__ ss,
                                                           int* __restrict__ si) {
  int hh = blockIdx.y;
  int mi = blockIdx.x * 256 + threadIdx.x;
  int rank = 0;
#pragma unroll
  for (int g = 0; g < SEG; g++) rank += partial[((size_t)hh * SEG + g) * NNODE + mi];
  ss[(size_t)hh * NNODE + rank] = s[(size_t)hh * NNODE + mi];
  si[(size_t)hh * NNODE + rank] = mi;
}

// Pass A: per-chunk partial sums of e^{s}*h (P) and e^{0.2s}*h (M); z at 128.
__global__ __launch_bounds__(128) void passA_kernel(const float* __restrict__ h,
                                                    const float* __restrict__ ss,
                                                    const int* __restrict__ si,
                                                    float* __restrict__ partP,
                                                    float* __restrict__ partM, int H) {
  __shared__ float eP[CHUNK], eM[CHUNK];
  __shared__ int ids[CHUNK];
  int b = blockIdx.x, hh = b / NCHUNK, ci = b % NCHUNK;
  int c = threadIdx.x;
  int HC = H * CDIM;
  int base = ci * CHUNK;
  if (c < CHUNK) {
    float sv = ss[(size_t)hh * NNODE + base + c];
    ids[c] = si[(size_t)hh * NNODE + base + c];
    eP[c] = expf(sv);
    eM[c] = expf(NEG * sv);
  }
  __syncthreads();
  float sp = 0.f, sm = 0.f;
  for (int kb = 0; kb < CHUNK; kb += 8) {
    float v[8];
#pragma unroll
    for (int j = 0; j < 8; j++)
      v[j] = h[(size_t)ids[kb + j] * HC + hh * CDIM + c];
#pragma unroll
    for (int j = 0; j < 8; j++) {
      sp = fmaf(eP[kb + j], v[j], sp);
      sm = fmaf(eM[kb + j], v[j], sm);
    }
  }
  size_t o = ((size_t)hh * NCHUNK + ci) * TW;
  partP[o + c] = sp;
  partM[o + c] = sm;
  if (c == 0) {
    float zp = 0.f, zm = 0.f;
#pragma unroll
    for (int k = 0; k < CHUNK; k++) { zp += eP[k]; zm += eM[k]; }
    partP[o + 128] = zp;
    partM[o + 128] = zm;
  }
}

// Pass C with fused BATCHED carry combine (16 independent loads in flight).
// LDS-staged gather + dual scan, z at col 128.
__global__ __launch_bounds__(128) void passC_kernel(const float* __restrict__ h,
                                                    const float* __restrict__ ss,
                                                    const int* __restrict__ si,
                                                    const float* __restrict__ partP,
                                                    const float* __restrict__ partM,
                                                    float* __restrict__ SS,
                                                    float* __restrict__ PP, int H) {
  __shared__ float hrow[CHUNK][CDIM];  // 32 KB
  __shared__ float eP[CHUNK], eM[CHUNK];
  __shared__ int ids[CHUNK];
  int b = blockIdx.x, hh = b / NCHUNK, ci = b % NCHUNK;
  int c = threadIdx.x;
  int HC = H * CDIM;
  int base = ci * CHUNK;
  size_t hb = (size_t)hh * (NNODE + 1);
  if (c < CHUNK) {
    float sv = ss[(size_t)hh * NNODE + base + c];
    ids[c] = si[(size_t)hh * NNODE + base + c];
    eP[c] = expf(sv);
    eM[c] = expf(NEG * sv);
  }
  __syncthreads();
  float cm = 0.f, cp = 0.f;
  for (int g0 = 0; g0 < NCHUNK; g0 += 16) {
    float vm[16], vp[16];
#pragma unroll
    for (int j = 0; j < 16; j++) {
      size_t o = ((size_t)hh * NCHUNK + g0 + j) * TW + c;
      vm[j] = partM[o];
      vp[j] = partP[o];
    }
#pragma unroll
    for (int j = 0; j < 16; j++) {
      if (g0 + j < ci) cm += vm[j];
      if (g0 + j > ci) cp += vp[j];
    }
  }
  float zcm = 0.f, zcp = 0.f;
  if (c == 0) {
    for (int g0 = 0; g0 < NCHUNK; g0 += 16) {
      float vm[16], vp[16];
#pragma unroll
      for (int j = 0; j < 16; j++) {
        size_t o = ((size_t)hh * NCHUNK + g0 + j) * TW + 128;
        vm[j] = partM[o];
        vp[j] = partP[o];
      }
#pragma unroll
      for (int j = 0; j < 16; j++) {
        if (g0 + j < ci) zcm += vm[j];
        if (g0 + j > ci) zcp += vp[j];
      }
    }
  }
  for (int kb = 0; kb < CHUNK; kb += 8) {
    float v[8];
#pragma unroll
    for (int j = 0; j < 8; j++)
      v[j] = h[(size_t)ids[kb + j] * HC + hh * CDIM + c];
#pragma unroll
    for (int j = 0; j < 8; j++) hrow[kb + j][c] = v[j];
  }
  float runm = zcm, runzm;
  // (use distinct accumulators: feature carry cm, z carry zcm)
  runm = cm; runzm = zcm;
#pragma unroll 8
  for (int k = 0; k < CHUNK; k++) {
    size_t row = (hb + base + k) * TW;
    PP[row + c] = runm;
    if (c == 0) PP[row + 128] = runzm;
    runm = fmaf(eM[k], hrow[k][c], runm);
    runzm += eM[k];
  }
  if (ci == NCHUNK - 1) {
    size_t row = (hb + NNODE) * TW;
    PP[row + c] = runm;
    if (c == 0) PP[row + 128] = runzm;
  }
  float runp = cp, runzp = zcp;
#pragma unroll 8
  for (int k = CHUNK - 1; k >= 0; k--) {
    runp = fmaf(eP[k], hrow[k][c], runp);
    runzp += eP[k];
    size_t row = (hb + base + k) * TW;
    SS[row + c] = runp;
    if (c == 0) SS[row + 128] = runzp;
  }
  if (ci == NCHUNK - 1) {
    size_t row = (hb + NNODE) * TW;
    SS[row + c] = 0.f;
    if (c == 0) SS[row + 128] = 0.f;
  }
}

// Per (dest, head): binary search split point, combine tables, +bias, ELU.
template <typename OUT>
__global__ __launch_bounds__(128) void attend_kernel(const float* __restrict__ SS,
                                                     const float* __restrict__ PP,
                                                     const float* __restrict__ ss,
                                                     const float* __restrict__ tt,
                                                     const float* __restrict__ bias,
                                                     OUT* __restrict__ out, int H) {
  int b = blockIdx.x;
  int n = b / H, hh = b % H;
  int c = threadIdx.x;
  float tv = tt[(size_t)hh * NNODE + n];
  const float* sp = ss + (size_t)hh * NNODE;
  float thr = -tv;
  int lo = 0, hi = NNODE;
  while (lo < hi) { int mid = (lo + hi) >> 1; if (sp[mid] < thr) lo = mid + 1; else hi = mid; }
  size_t hb = (size_t)hh * (NNODE + 1);
  float wp = expf(tv), wm = expf(NEG * tv);
  float num = wp * SS[(hb + lo) * TW + c] + wm * PP[(hb + lo) * TW + c];
  float Z = wp * SS[(hb + lo) * TW + 128] + wm * PP[(hb + lo) * TW + 128];
  float o = num / Z + bias[hh * CDIM + c];
  float r = (o > 0.f) ? o : (expf(o) - 1.f);
  if constexpr (sizeof(OUT) == 2)
    out[(size_t)n * (H * CDIM) + hh * CDIM + c] = f2b(r);
  else
    out[(size_t)n * (H * CDIM) + hh * CDIM + c] = r;
}

__global__ __launch_bounds__(256) void mean_kernel(const float* __restrict__ x,
                                                   float* __restrict__ m) {
  __shared__ float red[256];
  int c = blockIdx.x, tid = threadIdx.x;
  float acc = 0.f;
  for (int i = tid; i < NNODE; i += 256) acc += x[(size_t)i * CDIM + c];
  red[tid] = acc; __syncthreads();
  for (int o = 128; o > 0; o >>= 1) { if (tid < o) red[tid] += red[tid + o]; __syncthreads(); }
  if (tid == 0) m[c] = red[0] * (1.f / NNODE);
}

__global__ __launch_bounds__(256) void fc_kernel(const float* __restrict__ m,
                                                 const float* __restrict__ fcW,
                                                 const float* __restrict__ fcb,
                                                 float* __restrict__ out) {
  int d = blockIdx.x * 256 + threadIdx.x;  // 768 total
  float acc = fcb[d];
  for (int c2 = 0; c2 < CDIM; c2++) acc = fmaf(m[c2], fcW[c2 * 768 + d], acc);
  out[d] = acc;
}

extern "C" void kernel_launch(void* const* d_in, const int* in_sizes, int n_in,
                              void* d_out, int out_size, void* d_ws, size_t ws_size,
                              hipStream_t stream) {
  const float* x   = (const float*)d_in[0];
  const float* W1  = (const float*)d_in[1];
  const float* as1 = (const float*)d_in[2];
  const float* ad1 = (const float*)d_in[3];
  const float* b1  = (const float*)d_in[4];
  const float* W2  = (const float*)d_in[5];
  const float* as2 = (const float*)d_in[6];
  const float* ad2 = (const float*)d_in[7];
  const float* b2  = (const float*)d_in[8];
  const float* fcW = (const float*)d_in[9];
  const float* fcb = (const float*)d_in[10];

  float* ws = (float*)d_ws;
  size_t off = 0;
  auto alloc = [&](size_t nfloats) { float* p = ws + off; off += nfloats; return p; };

  float* h1  = alloc((size_t)NNODE * 512);
  float* x2f = alloc((size_t)NNODE * 256 + 64 + 16384);  // x2b bf16 + W2t bf16
  float* h2  = alloc((size_t)NNODE * 128);
  float* x3  = alloc((size_t)NNODE * 128);
  float* s1  = alloc((size_t)4 * NNODE);
  float* t1  = alloc((size_t)4 * NNODE);
  float* sS1 = alloc((size_t)4 * NNODE);
  int*   sI1 = (int*)alloc((size_t)4 * NNODE);
  float* SS1 = alloc((size_t)4 * (NNODE + 1) * TW);
  float* PP1 = alloc((size_t)4 * (NNODE + 1) * TW);
  float* pP1 = alloc((size_t)4 * NCHUNK * TW);
  float* pM1 = alloc((size_t)4 * NCHUNK * TW);
  float* s2  = alloc(NNODE);
  float* t2  = alloc(NNODE);
  float* sS2 = alloc(NNODE);
  int*   sI2 = (int*)alloc(NNODE);
  float* SS2 = alloc((size_t)(NNODE + 1) * TW);
  float* PP2 = alloc((size_t)(NNODE + 1) * TW);
  float* pP2 = alloc((size_t)NCHUNK * TW);
  float* pM2 = alloc((size_t)NCHUNK * TW);
  float* mv  = alloc(128);
  int*   rparts = (int*)alloc((size_t)4 * SEG * NNODE);

  // bf16 staging aliased into PP1/SS1 (first written by passC1, strictly after
  // gemm1 last reads them — stream ordered).
  unsigned short* xb  = (unsigned short*)PP1;  // 4096x768 bf16 = 6.3 MB (< 8.65 MB)
  unsigned short* W1t = (unsigned short*)SS1;  // 512x768 bf16
  unsigned short* x2b = (unsigned short*)x2f;                       // 4096x512 bf16
  unsigned short* W2t = (unsigned short*)(x2f + NNODE * 256 + 64);  // 128x512 bf16

  // Prep: convert x + transpose/cast W1, W2 (one kernel)
  prep_kernel<<<3072 + 96 + 16, 256, 0, stream>>>(x, W1, W2, xb, W1t, W2t);
  // Layer 1  (64x64 tiles -> 512 blocks, 2 blocks/CU, prefetched K-loop)
  mfma_gemm_bt<64, 64><<<dim3(512 / 64, NNODE / 64), 256, 0, stream>>>(xb, W1t, h1, NNODE, 512, 768);
  st_kernel<<<NNODE, 4 * 64, 0, stream>>>(h1, as1, ad1, s1, t1, 4);
  rank_count_kernel<<<dim3(NNODE / 256, SEG, 4), 256, 0, stream>>>(s1, rparts);
  rank_scatter_kernel<<<dim3(NNODE / 256, 4), 256, 0, stream>>>(s1, rparts, sS1, sI1);
  passA_kernel<<<4 * NCHUNK, 128, 0, stream>>>(h1, sS1, sI1, pP1, pM1, 4);
  passC_kernel<<<4 * NCHUNK, 128, 0, stream>>>(h1, sS1, sI1, pP1, pM1, SS1, PP1, 4);
  attend_kernel<unsigned short><<<NNODE * 4, 128, 0, stream>>>(SS1, PP1, sS1, t1, b1, x2b, 4);
  // Layer 2  (32x64 tiles -> 256 blocks)
  mfma_gemm_bt<32, 64><<<dim3(128 / 64, NNODE / 32), 256, 0, stream>>>(x2b, W2t, h2, NNODE, 128, 512);
  st_kernel<<<NNODE, 1 * 64, 0, stream>>>(h2, as2, ad2, s2, t2, 1);
  rank_count_kernel<<<dim3(NNODE / 256, SEG, 1), 256, 0, stream>>>(s2, rparts);
  rank_scatter_kernel<<<dim3(NNODE / 256, 1), 256, 0, stream>>>(s2, rparts, sS2, sI2);
  passA_kernel<<<NCHUNK, 128, 0, stream>>>(h2, sS2, sI2, pP2, pM2, 1);
  passC_kernel<<<NCHUNK, 128, 0, stream>>>(h2, sS2, sI2, pP2, pM2, SS2, PP2, 1);
  attend_kernel<float><<<NNODE, 128, 0, stream>>>(SS2, PP2, sS2, t2, b2, x3, 1);
  // Readout
  mean_kernel<<<128, 256, 0, stream>>>(x3, mv);
  fc_kernel<<<3, 256, 0, stream>>>(mv, fcW, fcb, (float*)d_out);
}